// Round 4
// baseline (47480.051 us; speedup 1.0000x reference)
//
#include <hip/hip_runtime.h>
#include <hip/hip_bf16.h>

typedef unsigned short u16;
typedef unsigned int u32;
typedef unsigned long long u64;

// ---------- sizes ----------
#define T_  8192
#define F_  1024
#define H_  2048
#define G_  8192   // 4*H

// ws layout (bytes). Total ~200 MB.
#define WS_XG    0                    // bf16 [T][G]          134217728
#define WS_ABF   134217728ull         // bf16 [T][F]           16777216
#define WS_WBF   150994944ull         // bf16 [G][F]           16777216
#define WS_HB    167772160ull         // bf16 [T][H]           33554432
#define WS_PART  201326592ull         // f32  [T][256]          8388608

#define SENTH 0x7F7Fu                 // bf16 3.38e38 — |h|<1 so never a real h

static __device__ __forceinline__ float bf2f(u16 u) {
    union { u32 i; float f; } x; x.i = ((u32)u) << 16; return x.f;
}
static __device__ __forceinline__ u16 f2bf(float f) {
    union { float f; u32 u; } x; x.f = f;
    u32 r = (x.u + 0x7fffu + ((x.u >> 16) & 1u)) >> 16;
    return (u16)r;
}

// ---------- fp32 -> bf16 convert (4 elems/thread) ----------
__global__ void cvt4_kernel(const float* __restrict__ s, u16* __restrict__ d, int n4) {
    int i = blockIdx.x * 256 + threadIdx.x;
    if (i < n4) {
        float4 v = ((const float4*)s)[i];
        union { u16 h[4]; uint2 v2; } o;
        o.h[0] = f2bf(v.x); o.h[1] = f2bf(v.y); o.h[2] = f2bf(v.z); o.h[3] = f2bf(v.w);
        ((uint2*)d)[i] = o.v2;
    }
}

// ---------- x_gates GEMM: xg[t][g] = sum_f A[t][f]*W[g][f] + b_ih[g]+b_hh[g] ----------
__global__ __launch_bounds__(256) void gemm_xg_kernel(
    const u16* __restrict__ A,   // [T][F] bf16
    const u16* __restrict__ W,   // [G][F] bf16
    const float* __restrict__ b_ih, const float* __restrict__ b_hh,
    u16* __restrict__ xg)        // [T][G] bf16
{
    __shared__ u16 As[64][40];
    __shared__ u16 Ws[64][40];

    const int tb = blockIdx.y * 64;
    const int gb = blockIdx.x * 64;
    const int tid  = threadIdx.x;
    const int wave = tid >> 6;
    const int lane = tid & 63;
    const int m    = lane & 15;
    const int quad = lane >> 4;

    const int lrow = tid >> 2;
    const int lcol = (tid & 3) * 8;

    using frag  = __attribute__((ext_vector_type(8))) short;
    using f32x4 = __attribute__((ext_vector_type(4))) float;
    f32x4 acc[4] = {};

    for (int k0 = 0; k0 < F_; k0 += 32) {
        __syncthreads();
        *(uint4*)&As[lrow][lcol] = *(const uint4*)&A[(size_t)(tb + lrow) * F_ + k0 + lcol];
        *(uint4*)&Ws[lrow][lcol] = *(const uint4*)&W[(size_t)(gb + lrow) * F_ + k0 + lcol];
        __syncthreads();
        frag bfr = *(const frag*)&Ws[wave * 16 + m][quad * 8];
#pragma unroll
        for (int i = 0; i < 4; ++i) {
            frag afr = *(const frag*)&As[i * 16 + m][quad * 8];
            acc[i] = __builtin_amdgcn_mfma_f32_16x16x32_bf16(afr, bfr, acc[i], 0, 0, 0);
        }
    }
    const int g = gb + wave * 16 + m;
    const float bias = b_ih[g] + b_hh[g];
#pragma unroll
    for (int i = 0; i < 4; ++i)
#pragma unroll
        for (int r = 0; r < 4; ++r) {
            int t = tb + i * 16 + quad * 4 + r;
            xg[(size_t)t * G_ + g] = f2bf(acc[i][r] + bias);
        }
}

// ---------- persistent LSTM recurrence, bf16 sentinel-dataflow sync ----------
// 256 blocks x 512 threads. Wave w of block b owns hidden unit uu=b*8+w.
// h published as bf16 (2B atomic store); hb[] pre-filled with 0x7F7F sentinel.
// Each consumer thread polls exactly ONE u64 (4 bf16), with s_sleep backoff.
__global__ __launch_bounds__(512, 2) void lstm_rec_kernel(
    const float* __restrict__ Whh,   // [G][H] f32
    const u16*  __restrict__ xg,     // [T][G] bf16
    const float* __restrict__ Wout,  // [H]
    u16*  __restrict__ hb,           // [T][H] bf16, pre-filled SENTH
    float* __restrict__ part)        // [T][256]
{
    __shared__ float hs[H_];
    __shared__ float pl[8];

    const int b   = blockIdx.x;
    const int tid = threadIdx.x;
    const int w   = tid >> 6;
    const int l   = tid & 63;
    const int uu  = b * 8 + w;          // hidden unit (wave-uniform)

    // preload weights: wreg[r][kc*4+j] = Whh[2048*r + uu][4*l + 256*kc + j]
    float wreg[4][32];
#pragma unroll
    for (int r = 0; r < 4; ++r) {
        const float* wrow = &Whh[(size_t)(2048 * r + uu) * H_];
#pragma unroll
        for (int kc = 0; kc < 8; ++kc) {
            float4 v = *(const float4*)&wrow[4 * l + 256 * kc];
            wreg[r][kc * 4 + 0] = v.x; wreg[r][kc * 4 + 1] = v.y;
            wreg[r][kc * 4 + 2] = v.z; wreg[r][kc * 4 + 3] = v.w;
        }
    }
    const float wout = Wout[uu];
    float c = 0.f;

    // h_{-1} = 0
    *(float4*)&hs[tid * 4] = make_float4(0.f, 0.f, 0.f, 0.f);
    __syncthreads();

    for (int t = 0; t < T_; ++t) {
        // prefetch this step's x-gate contributions (lane 0 only uses them)
        float xgi = 0.f, xgf = 0.f, xgg = 0.f, xgo = 0.f;
        if (l == 0) {
            const u16* xr = &xg[(size_t)t * G_ + uu];
            xgi = bf2f(xr[0]); xgf = bf2f(xr[2048]);
            xgg = bf2f(xr[4096]); xgo = bf2f(xr[6144]);
        }

        float a0 = 0.f, a1 = 0.f, a2 = 0.f, a3 = 0.f;
#pragma unroll
        for (int kc = 0; kc < 8; ++kc) {
            float4 hv = *(const float4*)&hs[4 * l + 256 * kc];
            a0 = fmaf(wreg[0][kc*4+0], hv.x, a0); a0 = fmaf(wreg[0][kc*4+1], hv.y, a0);
            a0 = fmaf(wreg[0][kc*4+2], hv.z, a0); a0 = fmaf(wreg[0][kc*4+3], hv.w, a0);
            a1 = fmaf(wreg[1][kc*4+0], hv.x, a1); a1 = fmaf(wreg[1][kc*4+1], hv.y, a1);
            a1 = fmaf(wreg[1][kc*4+2], hv.z, a1); a1 = fmaf(wreg[1][kc*4+3], hv.w, a1);
            a2 = fmaf(wreg[2][kc*4+0], hv.x, a2); a2 = fmaf(wreg[2][kc*4+1], hv.y, a2);
            a2 = fmaf(wreg[2][kc*4+2], hv.z, a2); a2 = fmaf(wreg[2][kc*4+3], hv.w, a2);
            a3 = fmaf(wreg[3][kc*4+0], hv.x, a3); a3 = fmaf(wreg[3][kc*4+1], hv.y, a3);
            a3 = fmaf(wreg[3][kc*4+2], hv.z, a3); a3 = fmaf(wreg[3][kc*4+3], hv.w, a3);
        }
#pragma unroll
        for (int off = 32; off >= 1; off >>= 1) {
            a0 += __shfl_down(a0, off);
            a1 += __shfl_down(a1, off);
            a2 += __shfl_down(a2, off);
            a3 += __shfl_down(a3, off);
        }

        if (l == 0) {
            float gi = a0 + xgi, gf = a1 + xgf, gg = a2 + xgg, go = a3 + xgo;
            float i_ = 1.f / (1.f + __expf(-gi));
            float f_ = 1.f / (1.f + __expf(-gf));
            float g_ = 1.f - 2.f / (__expf(2.f * gg) + 1.f);   // tanh
            float o_ = 1.f / (1.f + __expf(-go));
            c = fmaf(f_, c, i_ * g_);
            float th = 1.f - 2.f / (__expf(2.f * c) + 1.f);    // tanh
            float hval = o_ * th;
            // publish: bf16 data IS the flag (2B relaxed agent store)
            __hip_atomic_store(&hb[(size_t)t * H_ + uu], f2bf(hval),
                               __ATOMIC_RELAXED, __HIP_MEMORY_SCOPE_AGENT);
            pl[w] = hval * wout;
        }
        __syncthreads();   // hs reads done; pl[] complete; publishes issued

        // poll h_t: thread tid owns the single u64 covering bf16 units [4*tid,4*tid+4)
        {
            const u64* hp = (const u64*)(hb + (size_t)t * H_) + tid;
            u64 v = __hip_atomic_load(hp, __ATOMIC_RELAXED, __HIP_MEMORY_SCOPE_AGENT);
            while ((u16)v == SENTH || (u16)(v >> 16) == SENTH ||
                   (u16)(v >> 32) == SENTH || (u16)(v >> 48) == SENTH) {
                __builtin_amdgcn_s_sleep(1);
                v = __hip_atomic_load(hp, __ATOMIC_RELAXED, __HIP_MEMORY_SCOPE_AGENT);
            }
            union { u32 u[4]; float4 f; } hx;
            hx.u[0] = (u32)v << 16;
            hx.u[1] = (u32)v & 0xFFFF0000u;
            hx.u[2] = (u32)(v >> 32) << 16;
            hx.u[3] = (u32)(v >> 32) & 0xFFFF0000u;
            *(float4*)&hs[tid * 4] = hx.f;
        }
        __syncthreads();

        if (tid == 0) {
            part[(size_t)t * 256 + b] = pl[0] + pl[1] + pl[2] + pl[3]
                                      + pl[4] + pl[5] + pl[6] + pl[7];
        }
    }
}

// ---------- final: out[t] = b_out + sum_b part[t][b] ----------
__global__ __launch_bounds__(256) void out_reduce_kernel(
    const float* __restrict__ part, const float* __restrict__ b_out,
    float* __restrict__ out)
{
    int t = blockIdx.x * 4 + (threadIdx.x >> 6);
    int l = threadIdx.x & 63;
    const float* p = &part[(size_t)t * 256];
    float s = p[l] + p[l + 64] + p[l + 128] + p[l + 192];
#pragma unroll
    for (int off = 32; off >= 1; off >>= 1) s += __shfl_down(s, off);
    if (l == 0) out[t] = s + b_out[0];
}

extern "C" void kernel_launch(void* const* d_in, const int* in_sizes, int n_in,
                              void* d_out, int out_size, void* d_ws, size_t ws_size,
                              hipStream_t stream) {
    const float* input = (const float*)d_in[0];
    const float* W_ih  = (const float*)d_in[1];
    const float* W_hh  = (const float*)d_in[2];
    const float* b_ih  = (const float*)d_in[3];
    const float* b_hh  = (const float*)d_in[4];
    const float* W_out = (const float*)d_in[5];
    const float* b_out = (const float*)d_in[6];
    float* out = (float*)d_out;

    char* ws = (char*)d_ws;
    u16*   xg   = (u16*)(ws + WS_XG);
    u16*   Abf  = (u16*)(ws + WS_ABF);
    u16*   Wbf  = (u16*)(ws + WS_WBF);
    u16*   hb   = (u16*)(ws + WS_HB);
    float* part = (float*)(ws + WS_PART);

    // fill hb with bf16 sentinel (0x7f bytes -> 0x7F7F per u16)
    (void)hipMemsetAsync(hb, 0x7f, (size_t)T_ * H_ * sizeof(u16), stream);

    const int n4 = (T_ * F_) / 4;
    cvt4_kernel<<<(n4 + 255) / 256, 256, 0, stream>>>(input, Abf, n4);
    cvt4_kernel<<<(G_ * F_ / 4 + 255) / 256, 256, 0, stream>>>(W_ih, Wbf, G_ * F_ / 4);

    gemm_xg_kernel<<<dim3(G_ / 64, T_ / 64), 256, 0, stream>>>(Abf, Wbf, b_ih, b_hh, xg);

    lstm_rec_kernel<<<256, 512, 0, stream>>>(W_hh, xg, W_out, hb, part);

    out_reduce_kernel<<<T_ / 4, 256, 0, stream>>>(part, b_out, out);
}

// Round 5
// 30290.509 us; speedup vs baseline: 1.5675x; 1.5675x over previous
//
#include <hip/hip_runtime.h>
#include <hip/hip_bf16.h>

typedef unsigned short u16;
typedef unsigned int u32;
typedef unsigned long long u64;

// ---------- sizes ----------
#define T_  8192
#define F_  1024
#define H_  2048
#define G_  8192   // 4*H

#define NREG 8      // h-row replicas (poll-contention spreading)
#define DSLOT 4     // ring depth (skew bound is 2; 4 for margin)

// ws layout (bytes). Total ~170 MB.
#define WS_XG    0                    // bf16 [T][G]          134217728
#define WS_ABF   134217728ull         // bf16 [T][F]           16777216
#define WS_WBF   150994944ull         // bf16 [G][F]           16777216
#define WS_HX    167772160ull         // u64 [8][4][1024]        262144
#define WS_PART  168034304ull         // f32  [T][256]          8388608

static __device__ __forceinline__ float bf2f(u16 u) {
    union { u32 i; float f; } x; x.i = ((u32)u) << 16; return x.f;
}
static __device__ __forceinline__ u16 f2bf(float f) {
    union { float f; u32 u; } x; x.f = f;
    u32 r = (x.u + 0x7fffu + ((x.u >> 16) & 1u)) >> 16;
    return (u16)r;
}

// ---------- fp32 -> bf16 convert (4 elems/thread) ----------
__global__ void cvt4_kernel(const float* __restrict__ s, u16* __restrict__ d, int n4) {
    int i = blockIdx.x * 256 + threadIdx.x;
    if (i < n4) {
        float4 v = ((const float4*)s)[i];
        union { u16 h[4]; uint2 v2; } o;
        o.h[0] = f2bf(v.x); o.h[1] = f2bf(v.y); o.h[2] = f2bf(v.z); o.h[3] = f2bf(v.w);
        ((uint2*)d)[i] = o.v2;
    }
}

// ---------- x_gates GEMM: xg[t][g] = sum_f A[t][f]*W[g][f] + b_ih[g]+b_hh[g] ----------
__global__ __launch_bounds__(256) void gemm_xg_kernel(
    const u16* __restrict__ A,   // [T][F] bf16
    const u16* __restrict__ W,   // [G][F] bf16
    const float* __restrict__ b_ih, const float* __restrict__ b_hh,
    u16* __restrict__ xg)        // [T][G] bf16
{
    __shared__ u16 As[64][40];
    __shared__ u16 Ws[64][40];

    const int tb = blockIdx.y * 64;
    const int gb = blockIdx.x * 64;
    const int tid  = threadIdx.x;
    const int wave = tid >> 6;
    const int lane = tid & 63;
    const int m    = lane & 15;
    const int quad = lane >> 4;

    const int lrow = tid >> 2;
    const int lcol = (tid & 3) * 8;

    using frag  = __attribute__((ext_vector_type(8))) short;
    using f32x4 = __attribute__((ext_vector_type(4))) float;
    f32x4 acc[4] = {};

    for (int k0 = 0; k0 < F_; k0 += 32) {
        __syncthreads();
        *(uint4*)&As[lrow][lcol] = *(const uint4*)&A[(size_t)(tb + lrow) * F_ + k0 + lcol];
        *(uint4*)&Ws[lrow][lcol] = *(const uint4*)&W[(size_t)(gb + lrow) * F_ + k0 + lcol];
        __syncthreads();
        frag bfr = *(const frag*)&Ws[wave * 16 + m][quad * 8];
#pragma unroll
        for (int i = 0; i < 4; ++i) {
            frag afr = *(const frag*)&As[i * 16 + m][quad * 8];
            acc[i] = __builtin_amdgcn_mfma_f32_16x16x32_bf16(afr, bfr, acc[i], 0, 0, 0);
        }
    }
    const int g = gb + wave * 16 + m;
    const float bias = b_ih[g] + b_hh[g];
#pragma unroll
    for (int i = 0; i < 4; ++i)
#pragma unroll
        for (int r = 0; r < 4; ++r) {
            int t = tb + i * 16 + quad * 4 + r;
            xg[(size_t)t * G_ + g] = f2bf(acc[i][r] + bias);
        }
}

// ---------- persistent LSTM recurrence, tagged-slot replicated dataflow ----------
// 256 blocks x 512 threads. Wave w of block b owns hidden unit uu=b*8+w.
// Exchange: hx[8 regions][4 slots][1024 u64]; u64 = [h1:bf16|h0:bf16|tag:32=t].
// Producers replicate their 4 u64s to all 8 regions (32 stores, threads 0..31).
// Consumers poll region (b&7): thread tid spins on u64s tid and tid+512 until
// tag==t. No sentinel reset needed: tag mismatch IS the wait condition, and
// dataflow bounds inter-block skew to <=2 steps (slot reuse at t+4 is safe).
__global__ __launch_bounds__(512, 2) void lstm_rec_kernel(
    const float* __restrict__ Whh,   // [G][H] f32
    const u16*  __restrict__ xg,     // [T][G] bf16
    const float* __restrict__ Wout,  // [H]
    u64*  __restrict__ hx,           // pre-filled 0xFF (tag never matches)
    float* __restrict__ part)        // [T][256]
{
    __shared__ float hs[H_];
    __shared__ float hv8[8];
    __shared__ float pl[8];

    const int b   = blockIdx.x;
    const int tid = threadIdx.x;
    const int w   = tid >> 6;
    const int l   = tid & 63;
    const int uu  = b * 8 + w;          // hidden unit (wave-uniform)

    // preload weights: wreg[r][kc*4+j] = Whh[2048*r + uu][4*l + 256*kc + j]
    float wreg[4][32];
#pragma unroll
    for (int r = 0; r < 4; ++r) {
        const float* wrow = &Whh[(size_t)(2048 * r + uu) * H_];
#pragma unroll
        for (int kc = 0; kc < 8; ++kc) {
            float4 v = *(const float4*)&wrow[4 * l + 256 * kc];
            wreg[r][kc * 4 + 0] = v.x; wreg[r][kc * 4 + 1] = v.y;
            wreg[r][kc * 4 + 2] = v.z; wreg[r][kc * 4 + 3] = v.w;
        }
    }
    const float wout = Wout[uu];
    float c = 0.f;

    // h_{-1} = 0
    *(float4*)&hs[tid * 4] = make_float4(0.f, 0.f, 0.f, 0.f);
    __syncthreads();

    // xg software pipeline: regs hold step t's values (lane 0 only)
    float xgi = 0.f, xgf = 0.f, xgg = 0.f, xgo = 0.f;
    if (l == 0) {
        const u16* xr = &xg[uu];
        xgi = bf2f(xr[0]); xgf = bf2f(xr[2048]);
        xgg = bf2f(xr[4096]); xgo = bf2f(xr[6144]);
    }

    const u64* mypoll = hx + ((size_t)(b & 7) * DSLOT) * 1024;

    for (int t = 0; t < T_; ++t) {
        // prefetch next step's xg (full step of latency slack)
        float nxi = 0.f, nxf = 0.f, nxg = 0.f, nxo = 0.f;
        if (l == 0 && t + 1 < T_) {
            const u16* xr = &xg[(size_t)(t + 1) * G_ + uu];
            nxi = bf2f(xr[0]); nxf = bf2f(xr[2048]);
            nxg = bf2f(xr[4096]); nxo = bf2f(xr[6144]);
        }

        float a0 = 0.f, a1 = 0.f, a2 = 0.f, a3 = 0.f;
#pragma unroll
        for (int kc = 0; kc < 8; ++kc) {
            float4 hv = *(const float4*)&hs[4 * l + 256 * kc];
            a0 = fmaf(wreg[0][kc*4+0], hv.x, a0); a0 = fmaf(wreg[0][kc*4+1], hv.y, a0);
            a0 = fmaf(wreg[0][kc*4+2], hv.z, a0); a0 = fmaf(wreg[0][kc*4+3], hv.w, a0);
            a1 = fmaf(wreg[1][kc*4+0], hv.x, a1); a1 = fmaf(wreg[1][kc*4+1], hv.y, a1);
            a1 = fmaf(wreg[1][kc*4+2], hv.z, a1); a1 = fmaf(wreg[1][kc*4+3], hv.w, a1);
            a2 = fmaf(wreg[2][kc*4+0], hv.x, a2); a2 = fmaf(wreg[2][kc*4+1], hv.y, a2);
            a2 = fmaf(wreg[2][kc*4+2], hv.z, a2); a2 = fmaf(wreg[2][kc*4+3], hv.w, a2);
            a3 = fmaf(wreg[3][kc*4+0], hv.x, a3); a3 = fmaf(wreg[3][kc*4+1], hv.y, a3);
            a3 = fmaf(wreg[3][kc*4+2], hv.z, a3); a3 = fmaf(wreg[3][kc*4+3], hv.w, a3);
        }
#pragma unroll
        for (int off = 32; off >= 1; off >>= 1) {
            a0 += __shfl_down(a0, off);
            a1 += __shfl_down(a1, off);
            a2 += __shfl_down(a2, off);
            a3 += __shfl_down(a3, off);
        }

        if (l == 0) {
            float gi = a0 + xgi, gf = a1 + xgf, gg = a2 + xgg, go = a3 + xgo;
            float i_ = 1.f / (1.f + __expf(-gi));
            float f_ = 1.f / (1.f + __expf(-gf));
            float g_ = 1.f - 2.f / (__expf(2.f * gg) + 1.f);   // tanh
            float o_ = 1.f / (1.f + __expf(-go));
            c = fmaf(f_, c, i_ * g_);
            float th = 1.f - 2.f / (__expf(2.f * c) + 1.f);    // tanh
            float hval = o_ * th;
            hv8[w] = hval;
            pl[w] = hval * wout;
        }
        xgi = nxi; xgf = nxf; xgg = nxg; xgo = nxo;
        __syncthreads();   // hs reads done; hv8/pl complete

        const int slot = t & (DSLOT - 1);

        // publish: threads 0..31 — thread j stores u64 #(4b + j>>3) to region j&7
        if (tid < 32) {
            int q = tid >> 3, r = tid & 7;
            u32 p = (u32)f2bf(hv8[2 * q]) | ((u32)f2bf(hv8[2 * q + 1]) << 16);
            u64 v = ((u64)p << 32) | (u32)t;
            __hip_atomic_store(&hx[((size_t)(r * DSLOT + slot)) * 1024 + 4 * b + q], v,
                               __ATOMIC_RELAXED, __HIP_MEMORY_SCOPE_AGENT);
        }
        if (tid == 32) {
            part[(size_t)t * 256 + b] = pl[0] + pl[1] + pl[2] + pl[3]
                                      + pl[4] + pl[5] + pl[6] + pl[7];
        }

        // poll h_t from my region: u64s tid (units 2tid,2tid+1) and tid+512
        {
            const u64* pb = mypoll + (size_t)slot * 1024;
            u64 v0 = __hip_atomic_load(pb + tid,       __ATOMIC_RELAXED, __HIP_MEMORY_SCOPE_AGENT);
            u64 v1 = __hip_atomic_load(pb + tid + 512, __ATOMIC_RELAXED, __HIP_MEMORY_SCOPE_AGENT);
            while ((u32)v0 != (u32)t)
                v0 = __hip_atomic_load(pb + tid,       __ATOMIC_RELAXED, __HIP_MEMORY_SCOPE_AGENT);
            while ((u32)v1 != (u32)t)
                v1 = __hip_atomic_load(pb + tid + 512, __ATOMIC_RELAXED, __HIP_MEMORY_SCOPE_AGENT);
            hs[2 * tid]        = bf2f((u16)(v0 >> 32));
            hs[2 * tid + 1]    = bf2f((u16)(v0 >> 48));
            hs[1024 + 2 * tid] = bf2f((u16)(v1 >> 32));
            hs[1025 + 2 * tid] = bf2f((u16)(v1 >> 48));
        }
        __syncthreads();
    }
}

// ---------- final: out[t] = b_out + sum_b part[t][b] ----------
__global__ __launch_bounds__(256) void out_reduce_kernel(
    const float* __restrict__ part, const float* __restrict__ b_out,
    float* __restrict__ out)
{
    int t = blockIdx.x * 4 + (threadIdx.x >> 6);
    int l = threadIdx.x & 63;
    const float* p = &part[(size_t)t * 256];
    float s = p[l] + p[l + 64] + p[l + 128] + p[l + 192];
#pragma unroll
    for (int off = 32; off >= 1; off >>= 1) s += __shfl_down(s, off);
    if (l == 0) out[t] = s + b_out[0];
}

extern "C" void kernel_launch(void* const* d_in, const int* in_sizes, int n_in,
                              void* d_out, int out_size, void* d_ws, size_t ws_size,
                              hipStream_t stream) {
    const float* input = (const float*)d_in[0];
    const float* W_ih  = (const float*)d_in[1];
    const float* W_hh  = (const float*)d_in[2];
    const float* b_ih  = (const float*)d_in[3];
    const float* b_hh  = (const float*)d_in[4];
    const float* W_out = (const float*)d_in[5];
    const float* b_out = (const float*)d_in[6];
    float* out = (float*)d_out;

    char* ws = (char*)d_ws;
    u16*   xg   = (u16*)(ws + WS_XG);
    u16*   Abf  = (u16*)(ws + WS_ABF);
    u16*   Wbf  = (u16*)(ws + WS_WBF);
    u64*   hx   = (u64*)(ws + WS_HX);
    float* part = (float*)(ws + WS_PART);

    // tags init to 0xFFFFFFFF (never equals any t in [0,8192))
    (void)hipMemsetAsync(hx, 0xFF, (size_t)NREG * DSLOT * 1024 * sizeof(u64), stream);

    const int n4 = (T_ * F_) / 4;
    cvt4_kernel<<<(n4 + 255) / 256, 256, 0, stream>>>(input, Abf, n4);
    cvt4_kernel<<<(G_ * F_ / 4 + 255) / 256, 256, 0, stream>>>(W_ih, Wbf, G_ * F_ / 4);

    gemm_xg_kernel<<<dim3(G_ / 64, T_ / 64), 256, 0, stream>>>(Abf, Wbf, b_ih, b_hh, xg);

    lstm_rec_kernel<<<256, 512, 0, stream>>>(W_hh, xg, W_out, hx, part);

    out_reduce_kernel<<<T_ / 4, 256, 0, stream>>>(part, b_out, out);
}